// Round 14
// baseline (89.081 us; speedup 1.0000x reference)
//
#include <hip/hip_runtime.h>
#include <hip/hip_bf16.h>

typedef float f32x4 __attribute__((ext_vector_type(4)));
typedef _Float16 f16x2 __attribute__((ext_vector_type(2)));
typedef _Float16 f16x8 __attribute__((ext_vector_type(8)));

#define CC   64
#define HID  256
#define NOUT 64
#define HOUT 384
#define MAXCELL 16                // 16x16 tile: <=4 cell-rows x 4 cell-cols
#define CELLB 544                 // 512 data + 32 pad
#define UVB  (MAXCELL * CELLB)    // 8704
#define W2B  (UVB + 1024)         // 9728
#define SMEMB (W2B + 32768)       // 42496 B -> 3 blocks/CU (512 thr = 24 waves/CU)

// ---- k_prep: w2 -> W2F frags, w1[0:64] -> W1F frags, w1[64:66] -> UVH f16
__global__ __launch_bounds__(256) void k_prep(const float* __restrict__ w1,
                                              const float* __restrict__ w2,
                                              _Float16* __restrict__ W2F,
                                              _Float16* __restrict__ W1F,
                                              _Float16* __restrict__ UVH) {
    int idx = blockIdx.x * 256 + threadIdx.x;
    if (idx < 16384) {
        int f = idx, e = f & 7, l = (f >> 3) & 63, grp = f >> 9;
        int ks = grp >> 2, ng = grp & 3;
        int k = ks * 32 + ((l >> 4) << 3) + e;
        int n = (ng << 4) + (l & 15);
        W2F[f] = (_Float16)w2[k * NOUT + n];
    } else if (idx < 32768) {
        int f = idx - 16384, e = f & 7, l = (f >> 3) & 63, grp = f >> 9;
        int ks = grp >> 4, ng = grp & 15;
        int k = ks * 32 + ((l >> 4) << 3) + e;
        int n = (ng << 4) + (l & 15);
        W1F[f] = (_Float16)w1[k * HID + n];
    } else if (idx < 32768 + 512) {
        int f = idx - 32768;
        UVH[f] = (_Float16)w1[(CC + (f >> 8)) * HID + (f & 255)];
    }
}

// ---- k_gfeat (MFMA): G[cell][n] = b1[n] + sum_c res_f16[cell][c] * w1_f16[c][n]
__global__ __launch_bounds__(256) void k_gfeat(const float* __restrict__ res,
                                               const _Float16* __restrict__ W1F,
                                               const float* __restrict__ b1,
                                               _Float16* __restrict__ G) {
    const int cell0 = blockIdx.x * 32;
    const int b = cell0 >> 12, iyix0 = cell0 & 4095;
    const int tid = threadIdx.x;
    __shared__ _Float16 lds_a[32][72];
    __shared__ _Float16 lds_d[32][264];
    {
        int c = tid >> 2, cs = (tid & 3) * 8;
        const float* src = res + (((b * CC + c) << 12) + iyix0 + cs);
        f32x4 r0 = *(const f32x4*)src;
        f32x4 r1 = *(const f32x4*)(src + 4);
#pragma unroll
        for (int e = 0; e < 4; ++e) lds_a[cs + e][c] = (_Float16)r0[e];
#pragma unroll
        for (int e = 0; e < 4; ++e) lds_a[cs + 4 + e][c] = (_Float16)r1[e];
    }
    __syncthreads();
    const int wv = tid >> 6, l = tid & 63, lhi = l >> 4, dj = l & 15;
    const int crow = (wv & 1) * 16;
    const int nh = (wv >> 1) * 8;
    f32x4 acc[8];
#pragma unroll
    for (int q = 0; q < 8; ++q) {
        float bb = b1[(nh + q) * 16 + dj];
        acc[q] = (f32x4){bb, bb, bb, bb};
    }
#pragma unroll
    for (int ks = 0; ks < 2; ++ks) {
        f16x8 afr = *(const f16x8*)&lds_a[crow + dj][ks * 32 + lhi * 8];
#pragma unroll
        for (int q = 0; q < 8; ++q) {
            f16x8 bfr = *(const f16x8*)(W1F + (((ks * 16 + nh + q) * 64 + l) << 3));
            acc[q] = __builtin_amdgcn_mfma_f32_16x16x32_f16(afr, bfr, acc[q], 0, 0, 0);
        }
    }
#pragma unroll
    for (int q = 0; q < 8; ++q) {
        int n = (nh + q) * 16 + dj;
#pragma unroll
        for (int r = 0; r < 4; ++r)
            lds_d[crow + lhi * 4 + r][n] = (_Float16)acc[q][r];
    }
    __syncthreads();
    {
        int cell = tid >> 3, ch = (tid & 7) * 32;
        _Float16* dst = G + (((size_t)(cell0 + cell)) << 8) + ch;
#pragma unroll
        for (int r = 0; r < 4; ++r)
            *(f32x4*)(dst + r * 8) = *(const f32x4*)&lds_d[cell][ch + r * 8];
    }
}

// ---- main (templated): NOSTORE=1 is the diagnostic variant (no global
// stores, acc kept live via asm sinks) launched at 3x grid so it surfaces
// above the harness poison-fills in the rocprof top-5 with its own counters.
// NOSTORE=0 is the exact R12 kernel and runs LAST (correct output).
template<int NOSTORE>
__global__ __launch_bounds__(512, 2) void k_mainT(const _Float16* __restrict__ G,
                                                  const _Float16* __restrict__ W2F,
                                                  const _Float16* __restrict__ UVH,
                                                  const float* __restrict__ b2,
                                                  float* __restrict__ out) {
    const int jt = blockIdx.x;        // 0..23
    const int it = blockIdx.y;        // 0..23
    const int b  = blockIdx.z & 1;
    const int tid = threadIdx.x;
    const int wv = tid >> 6, l = tid & 63;
    const int lhi = l >> 4, dj = l & 15;
    const int i0 = it * 16, j0 = jt * 16;

    __shared__ char smem[SMEMB];

    // ---- integer staged-cell bounds
    const int r0 = i0 / 6;
    const int i15 = i0 + 15, ci15 = i15 / 6;
    const int r1 = min(ci15 + ((i15 - 6 * ci15) == 5 ? 1 : 0), 63);
    const int c0 = j0 / 6;
    const int j15 = j0 + 15, cj15 = j15 / 6;
    const int c1 = min(cj15 + ((j15 - 6 * cj15) == 5 ? 1 : 0), 63);
    const int ncc = c1 - c0 + 1;              // 3 or 4
    const int ncell = (r1 - r0 + 1) * ncc;    // <= 16

    // ---- stage: cells (one b128 per thread), uv, W2F (2 b128 per thread)
    if (tid < (ncell << 5)) {
        int cl = tid >> 5, c16 = tid & 31;
        int cr = (ncc == 4) ? (cl >> 2) : ((cl * 11) >> 5);
        int cc = cl - cr * ncc;
        const _Float16* src = G + (((size_t)((b << 12) + ((r0 + cr) << 6) + (c0 + cc))) << 8) + (c16 << 3);
        *(f32x4*)(smem + cl * CELLB + (c16 << 4)) = *(const f32x4*)src;
    }
    if (tid < 64)
        *(f32x4*)(smem + UVB + (tid << 4)) = *(const f32x4*)(UVH + (tid << 3));
    {
        const f32x4* w2g = (const f32x4*)W2F;
#pragma unroll
        for (int t = 0; t < 4; ++t)
            *(f32x4*)(smem + W2B + ((t * 512 + tid) << 4)) = w2g[t * 512 + tid];
    }
    float bbv[4];
#pragma unroll
    for (int ng = 0; ng < 4; ++ng) bbv[ng] = b2[(ng << 4) + dj];
    __syncthreads();

    // ---- x setup (per lane)
    const int j = j0 + dj;
    const int cj = j / 6, pj = j - 6 * cj;
    const bool xs = (pj == 5) && (cj < 63);
    const float rx0 = (float)(2 * pj - 5) * (1.f / 6.f);
    const float rx1 = xs ? rx0 - 2.f : rx0;

    // ---- y setup: strip A = row ia (even => pia in {0,2,4}), strip B = ia+1
    const int ia = i0 + (wv << 1);
    const int cia = ia / 6, pia = ia - 6 * cia;
    const float ryA = (float)(2 * pia - 5) * (1.f / 6.f);
    const float ryB = ryA + (1.f / 3.f);
    const bool ysB = (pia == 4) && (cia < 63);
    const float ryB1 = ysB ? ryB - 2.f : ryB;

    // strip A weights (ys=false folded)
    const float aA0 = fabsf(ryA * rx0) + 1e-9f;
    const float aA1 = fabsf(ryA * rx1) + 1e-9f;
    const float invA = 1.f / (aA0 + aA1);
    const float W00A = xs ? aA1 * invA : 1.f;
    const float W01A = xs ? aA0 * invA : 0.f;
    // strip B weights (general, diagonal swap)
    const float aB0 = fabsf(ryB * rx0) + 1e-9f;
    const float aB1 = fabsf(ryB * rx1) + 1e-9f;
    const float aB2 = fabsf(ryB1 * rx0) + 1e-9f;
    const float aB3 = fabsf(ryB1 * rx1) + 1e-9f;
    const float invB = 1.f / (aB0 + aB1 + aB2 + aB3);
    float W00B = aB3, W01B = 0.f, W10B = 0.f, W11B = 0.f;
    if (xs) W01B += aB2; else W00B += aB2;
    if (ysB) W10B += aB1; else W00B += aB1;
    if (ysB && xs) W11B += aB0;
    else if (ysB)  W10B += aB0;
    else if (xs)   W01B += aB0;
    else           W00B += aB0;
    W00B *= invB; W01B *= invB; W10B *= invB; W11B *= invB;

#define DUP2(x) (f16x2){(_Float16)(x), (_Float16)(x)}
    const f16x2 ryAh = DUP2(ryA), ryB1h = DUP2(ryB1);
    const f16x2 rx0h = DUP2(rx0), rx1h = DUP2(rx1);
    const f16x2 thirdh = DUP2(1.f / 3.f);
    const f16x2 W00Ah = DUP2(W00A), W01Ah = DUP2(W01A);
    const f16x2 W00Bh = DUP2(W00B), W01Bh = DUP2(W01B);
    const f16x2 W10h = DUP2(W10B), W11h = DUP2(W11B);
    const f16x2 zeroh = DUP2(0.f);

    const int lo16 = lhi << 4;
    const int rA = cia - r0;
    const int cm = cj - c0, cp = cm + (xs ? 1 : 0);
    const char* cell00 = smem + (rA * ncc + cm) * CELLB + lo16;
    const char* cell01 = smem + (rA * ncc + cp) * CELLB + lo16;
    const char* cell10 = cell00 + ncc * CELLB;
    const char* cell11 = cell01 + ncc * CELLB;
    const char* uvp = smem + UVB + lo16;
    const f16x8* w2l = (const f16x8*)(smem + W2B) + l;

    f32x4 acc[2][4];
#pragma unroll
    for (int s = 0; s < 2; ++s)
#pragma unroll
        for (int ng = 0; ng < 4; ++ng) acc[s][ng] = (f32x4){0.f, 0.f, 0.f, 0.f};

#pragma unroll
    for (int ks = 0; ks < 8; ++ks) {
        const int ko = ks * 64;
        f16x8 uraw = *(const f16x8*)(uvp + ko);
        f16x8 vraw = *(const f16x8*)(uvp + 512 + ko);
        const f16x2* uu = (const f16x2*)&uraw;
        const f16x2* vv = (const f16x2*)&vraw;
        f16x8 bfr[4];
#pragma unroll
        for (int ng = 0; ng < 4; ++ng) bfr[ng] = w2l[(ks * 4 + ng) * 64];
        f16x8 gv00 = *(const f16x8*)(cell00 + ko);
        f16x8 gv01 = *(const f16x8*)(cell01 + ko);
        const f16x2* g00 = (const f16x2*)&gv00;
        const f16x2* g01 = (const f16x2*)&gv01;
        f16x2 hA[4], hB[4];
#pragma unroll
        for (int e = 0; e < 4; ++e) {
            f16x2 t00 = g00[e] + ryAh * uu[e] + rx0h * vv[e];
            f16x2 t01 = g01[e] + ryAh * uu[e] + rx1h * vv[e];
            f16x2 t00B = t00 + thirdh * uu[e];      // strip B shares cells, ry+1/3
            f16x2 t01B = t01 + thirdh * uu[e];
            t00 = __builtin_elementwise_max(t00, zeroh);
            t01 = __builtin_elementwise_max(t01, zeroh);
            t00B = __builtin_elementwise_max(t00B, zeroh);
            t01B = __builtin_elementwise_max(t01B, zeroh);
            hA[e] = W00Ah * t00 + W01Ah * t01;
            hB[e] = W00Bh * t00B + W01Bh * t01B;
        }
        if (ysB) {                                   // wave-uniform
            f16x8 gv10 = *(const f16x8*)(cell10 + ko);
            f16x8 gv11 = *(const f16x8*)(cell11 + ko);
            const f16x2* g10 = (const f16x2*)&gv10;
            const f16x2* g11 = (const f16x2*)&gv11;
#pragma unroll
            for (int e = 0; e < 4; ++e) {
                f16x2 t10 = g10[e] + ryB1h * uu[e] + rx0h * vv[e];
                f16x2 t11 = g11[e] + ryB1h * uu[e] + rx1h * vv[e];
                hB[e] += W10h * __builtin_elementwise_max(t10, zeroh);
                hB[e] += W11h * __builtin_elementwise_max(t11, zeroh);
            }
        }
        f16x8 afA, afB;
#pragma unroll
        for (int e = 0; e < 4; ++e) {
            afA[2 * e] = hA[e][0]; afA[2 * e + 1] = hA[e][1];
            afB[2 * e] = hB[e][0]; afB[2 * e + 1] = hB[e][1];
        }
#pragma unroll
        for (int ng = 0; ng < 4; ++ng)
            acc[0][ng] = __builtin_amdgcn_mfma_f32_16x16x32_f16(afA, bfr[ng], acc[0][ng], 0, 0, 0);
#pragma unroll
        for (int ng = 0; ng < 4; ++ng)
            acc[1][ng] = __builtin_amdgcn_mfma_f32_16x16x32_f16(afB, bfr[ng], acc[1][ng], 0, 0, 0);
    }

    if constexpr (NOSTORE) {
        // keep the whole computation live without touching memory (rule 17)
#pragma unroll
        for (int s = 0; s < 2; ++s)
#pragma unroll
            for (int ng = 0; ng < 4; ++ng)
                asm volatile("" :: "v"(acc[s][ng][0]), "v"(acc[s][ng][1]),
                                   "v"(acc[s][ng][2]), "v"(acc[s][ng][3]));
    } else {
        // ---- epilogue: direct stores (D row = px col j0+lhi*4+r, D col = channel)
#pragma unroll
        for (int s = 0; s < 2; ++s) {
            const int irow = ia + s;
#pragma unroll
            for (int ng = 0; ng < 4; ++ng) {
                const int o = (ng << 4) + dj;
                float* op = out + (((size_t)b * NOUT + o) * HOUT + irow) * HOUT + j0 + (lhi << 2);
#pragma unroll
                for (int r = 0; r < 4; ++r)
                    op[r] = acc[s][ng][r] + bbv[ng];
            }
        }
    }
}

extern "C" void kernel_launch(void* const* d_in, const int* in_sizes, int n_in,
                              void* d_out, int out_size, void* d_ws, size_t ws_size,
                              hipStream_t stream) {
    const float* res = (const float*)d_in[0];
    const float* w1  = (const float*)d_in[1];
    const float* b1  = (const float*)d_in[2];
    const float* w2  = (const float*)d_in[3];
    const float* b2  = (const float*)d_in[4];
    float* out = (float*)d_out;

    char* ws = (char*)d_ws;
    _Float16* G   = (_Float16*)ws;                              // 4 MB
    _Float16* W2F = (_Float16*)(ws + (size_t)(8u << 20));       // 32 KB
    _Float16* W1F = (_Float16*)(ws + (size_t)(8u << 20) + 65536);
    _Float16* UVH = (_Float16*)(ws + (size_t)(8u << 20) + 131072);

    k_prep<<<130, 256, 0, stream>>>(w1, w2, W2F, W1F, UVH);
    k_gfeat<<<256, 256, 0, stream>>>(res, W1F, b1, G);
    // diagnostic: 3x grid, no stores -> surfaces above harness fills in top-5
    k_mainT<1><<<dim3(24, 24, 6), 512, 0, stream>>>(G, W2F, UVH, b2, out);
    // real run (exact R12 kernel), writes the validated output
    k_mainT<0><<<dim3(24, 24, 2), 512, 0, stream>>>(G, W2F, UVH, b2, out);
}

// Round 15
// 45.443 us; speedup vs baseline: 1.9603x; 1.9603x over previous
//
#include <hip/hip_runtime.h>
#include <hip/hip_bf16.h>

typedef float f32x4 __attribute__((ext_vector_type(4)));
typedef _Float16 f16x2 __attribute__((ext_vector_type(2)));
typedef _Float16 f16x8 __attribute__((ext_vector_type(8)));

#define CC   64
#define HID  256
#define NOUT 64
#define HOUT 384
#define MAXCELL 16
#define CELLB 512                 // NO pad: gload_lds needs linear dest; cell/uv
                                  // reads are wave-uniform broadcasts (no conflict)
#define UVB  (MAXCELL * CELLB)    // 8192
#define W2B  (UVB + 1024)         // 9216
#define SMEMB (W2B + 32768)       // 41984 B -> 3 blocks/CU

#define LDS_PTR(p) ((__attribute__((address_space(3))) void*)(p))
#define GLB_PTR(p) ((const __attribute__((address_space(1))) void*)(p))
__device__ __forceinline__ void gload_lds16(const void* g, void* l) {
    __builtin_amdgcn_global_load_lds(GLB_PTR(g), LDS_PTR(l), 16, 0, 0);
}

// ---- k_prep: w2 -> W2F frags, w1[0:64] -> W1F frags, w1[64:66] -> UVH f16
__global__ __launch_bounds__(256) void k_prep(const float* __restrict__ w1,
                                              const float* __restrict__ w2,
                                              _Float16* __restrict__ W2F,
                                              _Float16* __restrict__ W1F,
                                              _Float16* __restrict__ UVH) {
    int idx = blockIdx.x * 256 + threadIdx.x;
    if (idx < 16384) {
        int f = idx, e = f & 7, l = (f >> 3) & 63, grp = f >> 9;
        int ks = grp >> 2, ng = grp & 3;
        int k = ks * 32 + ((l >> 4) << 3) + e;
        int n = (ng << 4) + (l & 15);
        W2F[f] = (_Float16)w2[k * NOUT + n];
    } else if (idx < 32768) {
        int f = idx - 16384, e = f & 7, l = (f >> 3) & 63, grp = f >> 9;
        int ks = grp >> 4, ng = grp & 15;
        int k = ks * 32 + ((l >> 4) << 3) + e;
        int n = (ng << 4) + (l & 15);
        W1F[f] = (_Float16)w1[k * HID + n];
    } else if (idx < 32768 + 512) {
        int f = idx - 32768;
        UVH[f] = (_Float16)w1[(CC + (f >> 8)) * HID + (f & 255)];
    }
}

// ---- k_gfeat (MFMA): G[cell][n] = b1[n] + sum_c res_f16[cell][c] * w1_f16[c][n]
__global__ __launch_bounds__(256) void k_gfeat(const float* __restrict__ res,
                                               const _Float16* __restrict__ W1F,
                                               const float* __restrict__ b1,
                                               _Float16* __restrict__ G) {
    const int cell0 = blockIdx.x * 32;
    const int b = cell0 >> 12, iyix0 = cell0 & 4095;
    const int tid = threadIdx.x;
    __shared__ _Float16 lds_a[32][72];
    __shared__ _Float16 lds_d[32][264];
    {
        int c = tid >> 2, cs = (tid & 3) * 8;
        const float* src = res + (((b * CC + c) << 12) + iyix0 + cs);
        f32x4 r0 = *(const f32x4*)src;
        f32x4 r1 = *(const f32x4*)(src + 4);
#pragma unroll
        for (int e = 0; e < 4; ++e) lds_a[cs + e][c] = (_Float16)r0[e];
#pragma unroll
        for (int e = 0; e < 4; ++e) lds_a[cs + 4 + e][c] = (_Float16)r1[e];
    }
    __syncthreads();
    const int wv = tid >> 6, l = tid & 63, lhi = l >> 4, dj = l & 15;
    const int crow = (wv & 1) * 16;
    const int nh = (wv >> 1) * 8;
    f32x4 acc[8];
#pragma unroll
    for (int q = 0; q < 8; ++q) {
        float bb = b1[(nh + q) * 16 + dj];
        acc[q] = (f32x4){bb, bb, bb, bb};
    }
#pragma unroll
    for (int ks = 0; ks < 2; ++ks) {
        f16x8 afr = *(const f16x8*)&lds_a[crow + dj][ks * 32 + lhi * 8];
#pragma unroll
        for (int q = 0; q < 8; ++q) {
            f16x8 bfr = *(const f16x8*)(W1F + (((ks * 16 + nh + q) * 64 + l) << 3));
            acc[q] = __builtin_amdgcn_mfma_f32_16x16x32_f16(afr, bfr, acc[q], 0, 0, 0);
        }
    }
#pragma unroll
    for (int q = 0; q < 8; ++q) {
        int n = (nh + q) * 16 + dj;
#pragma unroll
        for (int r = 0; r < 4; ++r)
            lds_d[crow + lhi * 4 + r][n] = (_Float16)acc[q][r];
    }
    __syncthreads();
    {
        int cell = tid >> 3, ch = (tid & 7) * 32;
        _Float16* dst = G + (((size_t)(cell0 + cell)) << 8) + ch;
#pragma unroll
        for (int r = 0; r < 4; ++r)
            *(f32x4*)(dst + r * 8) = *(const f32x4*)&lds_d[cell][ch + r * 8];
    }
}

// ---- main: block = 8 waves (512 thr), tile = 16x16 px, processes b=0 THEN
// b=1 (same setup/weights/LDS slots). b0 stores overlap b1 restage+compute:
//   lgkm0+bar -> gload_lds(b1 cells) -> b0 stores -> vmcnt(8) (stores fly) -> bar
__global__ __launch_bounds__(512, 2) void k_main(const _Float16* __restrict__ G,
                                                 const _Float16* __restrict__ W2F,
                                                 const _Float16* __restrict__ UVH,
                                                 const float* __restrict__ b2,
                                                 float* __restrict__ out) {
    const int jt = blockIdx.x;        // 0..23
    const int it = blockIdx.y;        // 0..23
    const int tid = threadIdx.x;
    const int wv = tid >> 6, l = tid & 63;
    const int lhi = l >> 4, dj = l & 15;
    const int i0 = it * 16, j0 = jt * 16;

    __shared__ char smem[SMEMB];

    // ---- integer staged-cell bounds
    const int r0 = i0 / 6;
    const int i15 = i0 + 15, ci15 = i15 / 6;
    const int r1 = min(ci15 + ((i15 - 6 * ci15) == 5 ? 1 : 0), 63);
    const int c0 = j0 / 6;
    const int j15 = j0 + 15, cj15 = j15 / 6;
    const int c1 = min(cj15 + ((j15 - 6 * cj15) == 5 ? 1 : 0), 63);
    const int ncc = c1 - c0 + 1;              // 3 or 4
    const int ncell = (r1 - r0 + 1) * ncc;    // 9..16

    // per-lane global source for this wave's cell pair (cl = wv*2 + (l>>5))
    const int myCl = (wv << 1) + (l >> 5);
    int mcr = (ncc == 4) ? (myCl >> 2) : ((myCl * 11) >> 5);
    int mcc = myCl - mcr * ncc;
    const size_t cellGBase = ((size_t)(((r0 + mcr) << 6) + (c0 + mcc)) << 8) + ((l & 31) << 3);
    char* cellLBase = smem + (wv << 10);      // wave-uniform, lane*16 auto

    // ---- initial stage: cells(b0) + uv + W2F, all via global_load_lds
    if (myCl < ncell)
        gload_lds16(G + cellGBase, cellLBase);
    if (wv == 0)
        gload_lds16(UVH + (l << 3), smem + UVB);
#pragma unroll
    for (int c = 0; c < 4; ++c)
        gload_lds16(W2F + (wv << 9) + (c << 12) + (l << 3),
                    smem + W2B + (wv << 10) + (c << 13));
    float bbv[4];
#pragma unroll
    for (int ng = 0; ng < 4; ++ng) bbv[ng] = b2[(ng << 4) + dj];
    __syncthreads();   // vmcnt(0)+lgkmcnt(0)+barrier: all staging landed

    // ---- x setup (per lane)
    const int j = j0 + dj;
    const int cj = j / 6, pj = j - 6 * cj;
    const bool xs = (pj == 5) && (cj < 63);
    const float rx0 = (float)(2 * pj - 5) * (1.f / 6.f);
    const float rx1 = xs ? rx0 - 2.f : rx0;

    // ---- y setup: strip A = row ia (even), strip B = ia+1
    const int ia = i0 + (wv << 1);
    const int cia = ia / 6, pia = ia - 6 * cia;
    const float ryA = (float)(2 * pia - 5) * (1.f / 6.f);
    const float ryB = ryA + (1.f / 3.f);
    const bool ysB = (pia == 4) && (cia < 63);
    const float ryB1 = ysB ? ryB - 2.f : ryB;

    const float aA0 = fabsf(ryA * rx0) + 1e-9f;
    const float aA1 = fabsf(ryA * rx1) + 1e-9f;
    const float invA = 1.f / (aA0 + aA1);
    const float W00A = xs ? aA1 * invA : 1.f;
    const float W01A = xs ? aA0 * invA : 0.f;
    const float aB0 = fabsf(ryB * rx0) + 1e-9f;
    const float aB1 = fabsf(ryB * rx1) + 1e-9f;
    const float aB2 = fabsf(ryB1 * rx0) + 1e-9f;
    const float aB3 = fabsf(ryB1 * rx1) + 1e-9f;
    const float invB = 1.f / (aB0 + aB1 + aB2 + aB3);
    float W00B = aB3, W01B = 0.f, W10B = 0.f, W11B = 0.f;
    if (xs) W01B += aB2; else W00B += aB2;
    if (ysB) W10B += aB1; else W00B += aB1;
    if (ysB && xs) W11B += aB0;
    else if (ysB)  W10B += aB0;
    else if (xs)   W01B += aB0;
    else           W00B += aB0;
    W00B *= invB; W01B *= invB; W10B *= invB; W11B *= invB;

#define DUP2(x) (f16x2){(_Float16)(x), (_Float16)(x)}
    const f16x2 ryAh = DUP2(ryA), ryB1h = DUP2(ryB1);
    const f16x2 rx0h = DUP2(rx0), rx1h = DUP2(rx1);
    const f16x2 thirdh = DUP2(1.f / 3.f);
    const f16x2 W00Ah = DUP2(W00A), W01Ah = DUP2(W01A);
    const f16x2 W00Bh = DUP2(W00B), W01Bh = DUP2(W01B);
    const f16x2 W10h = DUP2(W10B), W11h = DUP2(W11B);
    const f16x2 zeroh = DUP2(0.f);

    const int lo16 = lhi << 4;
    const int rA = cia - r0;
    const int cm = cj - c0, cp = cm + (xs ? 1 : 0);
    const char* cell00 = smem + ((rA * ncc + cm) << 9) + lo16;
    const char* cell01 = smem + ((rA * ncc + cp) << 9) + lo16;
    const char* cell10 = cell00 + (ncc << 9);
    const char* cell11 = cell01 + (ncc << 9);
    const char* uvp = smem + UVB + lo16;
    const f16x8* w2l = (const f16x8*)(smem + W2B) + l;

    f32x4 acc[2][4];

    auto compute = [&]() {
#pragma unroll
        for (int s = 0; s < 2; ++s)
#pragma unroll
            for (int ng = 0; ng < 4; ++ng) acc[s][ng] = (f32x4){0.f, 0.f, 0.f, 0.f};
#pragma unroll
        for (int ks = 0; ks < 8; ++ks) {
            const int ko = ks * 64;
            f16x8 uraw = *(const f16x8*)(uvp + ko);
            f16x8 vraw = *(const f16x8*)(uvp + 512 + ko);
            const f16x2* uu = (const f16x2*)&uraw;
            const f16x2* vv = (const f16x2*)&vraw;
            f16x8 bfr[4];
#pragma unroll
            for (int ng = 0; ng < 4; ++ng) bfr[ng] = w2l[(ks * 4 + ng) * 64];
            f16x8 gv00 = *(const f16x8*)(cell00 + ko);
            f16x8 gv01 = *(const f16x8*)(cell01 + ko);
            const f16x2* g00 = (const f16x2*)&gv00;
            const f16x2* g01 = (const f16x2*)&gv01;
            union { f16x2 h2[4]; f16x8 v8; } HA, HB;
#pragma unroll
            for (int e = 0; e < 4; ++e) {
                f16x2 t00 = g00[e] + ryAh * uu[e] + rx0h * vv[e];
                f16x2 t01 = g01[e] + ryAh * uu[e] + rx1h * vv[e];
                f16x2 t00B = t00 + thirdh * uu[e];
                f16x2 t01B = t01 + thirdh * uu[e];
                t00 = __builtin_elementwise_max(t00, zeroh);
                t01 = __builtin_elementwise_max(t01, zeroh);
                t00B = __builtin_elementwise_max(t00B, zeroh);
                t01B = __builtin_elementwise_max(t01B, zeroh);
                HA.h2[e] = W00Ah * t00 + W01Ah * t01;
                HB.h2[e] = W00Bh * t00B + W01Bh * t01B;
            }
            if (ysB) {
                f16x8 gv10 = *(const f16x8*)(cell10 + ko);
                f16x8 gv11 = *(const f16x8*)(cell11 + ko);
                const f16x2* g10 = (const f16x2*)&gv10;
                const f16x2* g11 = (const f16x2*)&gv11;
#pragma unroll
                for (int e = 0; e < 4; ++e) {
                    f16x2 t10 = g10[e] + ryB1h * uu[e] + rx0h * vv[e];
                    f16x2 t11 = g11[e] + ryB1h * uu[e] + rx1h * vv[e];
                    HB.h2[e] += W10h * __builtin_elementwise_max(t10, zeroh);
                    HB.h2[e] += W11h * __builtin_elementwise_max(t11, zeroh);
                }
            }
#pragma unroll
            for (int ng = 0; ng < 4; ++ng)
                acc[0][ng] = __builtin_amdgcn_mfma_f32_16x16x32_f16(HA.v8, bfr[ng], acc[0][ng], 0, 0, 0);
#pragma unroll
            for (int ng = 0; ng < 4; ++ng)
                acc[1][ng] = __builtin_amdgcn_mfma_f32_16x16x32_f16(HB.v8, bfr[ng], acc[1][ng], 0, 0, 0);
        }
    };

    auto store_tile = [&](int b) {
#pragma unroll
        for (int s = 0; s < 2; ++s) {
            const int irow = ia + s;
#pragma unroll
            for (int ng = 0; ng < 4; ++ng) {
                const int o = (ng << 4) + dj;
                float* op = out + (((size_t)b * NOUT + o) * HOUT + irow) * HOUT + j0 + (lhi << 2);
#pragma unroll
                for (int r = 0; r < 4; ++r)
                    op[r] = acc[s][ng][r] + bbv[ng];
            }
        }
    };

    // ---- tile b=0
    compute();
    // ---- transition: restage b1 cells, overlap b0 stores with b1 compute
    asm volatile("s_waitcnt lgkmcnt(0)" ::: "memory");
    __builtin_amdgcn_s_barrier();             // all waves done reading b0 cells
    __builtin_amdgcn_sched_barrier(0);
    if (myCl < ncell)
        gload_lds16(G + ((size_t)1 << 20) + cellGBase, cellLBase);  // b=1: +4096 cells *256
    __builtin_amdgcn_sched_barrier(0);        // stores must stay AFTER the load
    store_tile(0);
    __builtin_amdgcn_sched_barrier(0);
    asm volatile("s_waitcnt vmcnt(8)" ::: "memory");  // cell load landed; stores in flight
    __builtin_amdgcn_s_barrier();
    __builtin_amdgcn_sched_barrier(0);
    // ---- tile b=1
    compute();
    store_tile(1);
}

extern "C" void kernel_launch(void* const* d_in, const int* in_sizes, int n_in,
                              void* d_out, int out_size, void* d_ws, size_t ws_size,
                              hipStream_t stream) {
    const float* res = (const float*)d_in[0];
    const float* w1  = (const float*)d_in[1];
    const float* b1  = (const float*)d_in[2];
    const float* w2  = (const float*)d_in[3];
    const float* b2  = (const float*)d_in[4];
    float* out = (float*)d_out;

    char* ws = (char*)d_ws;
    _Float16* G   = (_Float16*)ws;                              // 4 MB
    _Float16* W2F = (_Float16*)(ws + (size_t)(8u << 20));       // 32 KB
    _Float16* W1F = (_Float16*)(ws + (size_t)(8u << 20) + 65536);
    _Float16* UVH = (_Float16*)(ws + (size_t)(8u << 20) + 131072);

    k_prep<<<130, 256, 0, stream>>>(w1, w2, W2F, W1F, UVH);
    k_gfeat<<<256, 256, 0, stream>>>(res, W1F, b1, G);
    k_main<<<dim3(24, 24, 1), 512, 0, stream>>>(G, W2F, UVH, b2, out);
}

// Round 16
// 40.799 us; speedup vs baseline: 2.1834x; 1.1138x over previous
//
#include <hip/hip_runtime.h>
#include <hip/hip_bf16.h>

typedef float f32x4 __attribute__((ext_vector_type(4)));
typedef _Float16 f16x2 __attribute__((ext_vector_type(2)));
typedef _Float16 f16x8 __attribute__((ext_vector_type(8)));

#define CC   64
#define HID  256
#define NOUT 64
#define HOUT 384
#define MAXCELL 16                // 16x16 tile: <=4 cell-rows x 4 cell-cols
#define CELLB 512                 // cell/uv reads are wave-uniform broadcasts -> no pad needed
#define UVB  (MAXCELL * CELLB)    // 8192
#define SMEMB (UVB + 1024)        // 9216 B -> LDS no longer the occupancy limiter

// ---- k_prep: w2 -> W2F frags, w1[0:64] -> W1F frags, w1[64:66] -> UVH f16
__global__ __launch_bounds__(256) void k_prep(const float* __restrict__ w1,
                                              const float* __restrict__ w2,
                                              _Float16* __restrict__ W2F,
                                              _Float16* __restrict__ W1F,
                                              _Float16* __restrict__ UVH) {
    int idx = blockIdx.x * 256 + threadIdx.x;
    if (idx < 16384) {
        int f = idx, e = f & 7, l = (f >> 3) & 63, grp = f >> 9;
        int ks = grp >> 2, ng = grp & 3;
        int k = ks * 32 + ((l >> 4) << 3) + e;
        int n = (ng << 4) + (l & 15);
        W2F[f] = (_Float16)w2[k * NOUT + n];
    } else if (idx < 32768) {
        int f = idx - 16384, e = f & 7, l = (f >> 3) & 63, grp = f >> 9;
        int ks = grp >> 4, ng = grp & 15;
        int k = ks * 32 + ((l >> 4) << 3) + e;
        int n = (ng << 4) + (l & 15);
        W1F[f] = (_Float16)w1[k * HID + n];
    } else if (idx < 32768 + 512) {
        int f = idx - 32768;
        UVH[f] = (_Float16)w1[(CC + (f >> 8)) * HID + (f & 255)];
    }
}

// ---- k_gfeat (MFMA): G[cell][n] = b1[n] + sum_c res_f16[cell][c] * w1_f16[c][n]
__global__ __launch_bounds__(256) void k_gfeat(const float* __restrict__ res,
                                               const _Float16* __restrict__ W1F,
                                               const float* __restrict__ b1,
                                               _Float16* __restrict__ G) {
    const int cell0 = blockIdx.x * 32;
    const int b = cell0 >> 12, iyix0 = cell0 & 4095;
    const int tid = threadIdx.x;
    __shared__ _Float16 lds_a[32][72];
    __shared__ _Float16 lds_d[32][264];
    {
        int c = tid >> 2, cs = (tid & 3) * 8;
        const float* src = res + (((b * CC + c) << 12) + iyix0 + cs);
        f32x4 r0 = *(const f32x4*)src;
        f32x4 r1 = *(const f32x4*)(src + 4);
#pragma unroll
        for (int e = 0; e < 4; ++e) lds_a[cs + e][c] = (_Float16)r0[e];
#pragma unroll
        for (int e = 0; e < 4; ++e) lds_a[cs + 4 + e][c] = (_Float16)r1[e];
    }
    __syncthreads();
    const int wv = tid >> 6, l = tid & 63, lhi = l >> 4, dj = l & 15;
    const int crow = (wv & 1) * 16;
    const int nh = (wv >> 1) * 8;
    f32x4 acc[8];
#pragma unroll
    for (int q = 0; q < 8; ++q) {
        float bb = b1[(nh + q) * 16 + dj];
        acc[q] = (f32x4){bb, bb, bb, bb};
    }
#pragma unroll
    for (int ks = 0; ks < 2; ++ks) {
        f16x8 afr = *(const f16x8*)&lds_a[crow + dj][ks * 32 + lhi * 8];
#pragma unroll
        for (int q = 0; q < 8; ++q) {
            f16x8 bfr = *(const f16x8*)(W1F + (((ks * 16 + nh + q) * 64 + l) << 3));
            acc[q] = __builtin_amdgcn_mfma_f32_16x16x32_f16(afr, bfr, acc[q], 0, 0, 0);
        }
    }
#pragma unroll
    for (int q = 0; q < 8; ++q) {
        int n = (nh + q) * 16 + dj;
#pragma unroll
        for (int r = 0; r < 4; ++r)
            lds_d[crow + lhi * 4 + r][n] = (_Float16)acc[q][r];
    }
    __syncthreads();
    {
        int cell = tid >> 3, ch = (tid & 7) * 32;
        _Float16* dst = G + (((size_t)(cell0 + cell)) << 8) + ch;
#pragma unroll
        for (int r = 0; r < 4; ++r)
            *(f32x4*)(dst + r * 8) = *(const f32x4*)&lds_d[cell][ch + r * 8];
    }
}

// ---- main: block = 8 waves (512 thr), tile = 16 rows x 16 cols; wave = 2
// adjacent rows sharing one cell-row. ks-outer loop. Cells+uv in LDS; w2
// fragments read from GLOBAL (L1-resident 32 KB, coalesced 1 KB/load) —
// R4 vs R5 showed VMEM-w2 == LDS-w2 even at low occupancy.
__global__ __launch_bounds__(512, 2) void k_main(const _Float16* __restrict__ G,
                                                 const _Float16* __restrict__ W2F,
                                                 const _Float16* __restrict__ UVH,
                                                 const float* __restrict__ b2,
                                                 float* __restrict__ out) {
    const int jt = blockIdx.x;        // 0..23
    const int it = blockIdx.y;        // 0..23
    const int b  = blockIdx.z;        // 0..1
    const int tid = threadIdx.x;
    const int wv = tid >> 6, l = tid & 63;
    const int lhi = l >> 4, dj = l & 15;
    const int i0 = it * 16, j0 = jt * 16;

    __shared__ char smem[SMEMB];

    // ---- integer staged-cell bounds
    const int r0 = i0 / 6;
    const int i15 = i0 + 15, ci15 = i15 / 6;
    const int r1 = min(ci15 + ((i15 - 6 * ci15) == 5 ? 1 : 0), 63);
    const int c0 = j0 / 6;
    const int j15 = j0 + 15, cj15 = j15 / 6;
    const int c1 = min(cj15 + ((j15 - 6 * cj15) == 5 ? 1 : 0), 63);
    const int ncc = c1 - c0 + 1;              // 3 or 4
    const int ncell = (r1 - r0 + 1) * ncc;    // 9..16

    // ---- stage: cells (one f32x4 per thread) + uv
    if (tid < (ncell << 5)) {
        int cl = tid >> 5, c16 = tid & 31;
        int cr = (ncc == 4) ? (cl >> 2) : ((cl * 11) >> 5);
        int cc = cl - cr * ncc;
        const _Float16* src = G + (((size_t)((b << 12) + ((r0 + cr) << 6) + (c0 + cc))) << 8) + (c16 << 3);
        *(f32x4*)(smem + (cl << 9) + (c16 << 4)) = *(const f32x4*)src;
    }
    if (tid < 64)
        *(f32x4*)(smem + UVB + (tid << 4)) = *(const f32x4*)(UVH + (tid << 3));
    float bbv[4];
#pragma unroll
    for (int ng = 0; ng < 4; ++ng) bbv[ng] = b2[(ng << 4) + dj];
    __syncthreads();

    // ---- x setup (per lane)
    const int j = j0 + dj;
    const int cj = j / 6, pj = j - 6 * cj;
    const bool xs = (pj == 5) && (cj < 63);
    const float rx0 = (float)(2 * pj - 5) * (1.f / 6.f);
    const float rx1 = xs ? rx0 - 2.f : rx0;

    // ---- y setup: strip A = row ia (even => pia in {0,2,4}), strip B = ia+1
    const int ia = i0 + (wv << 1);
    const int cia = ia / 6, pia = ia - 6 * cia;
    const float ryA = (float)(2 * pia - 5) * (1.f / 6.f);
    const float ryB = ryA + (1.f / 3.f);
    const bool ysB = (pia == 4) && (cia < 63);
    const float ryB1 = ysB ? ryB - 2.f : ryB;

    const float aA0 = fabsf(ryA * rx0) + 1e-9f;
    const float aA1 = fabsf(ryA * rx1) + 1e-9f;
    const float invA = 1.f / (aA0 + aA1);
    const float W00A = xs ? aA1 * invA : 1.f;
    const float W01A = xs ? aA0 * invA : 0.f;
    const float aB0 = fabsf(ryB * rx0) + 1e-9f;
    const float aB1 = fabsf(ryB * rx1) + 1e-9f;
    const float aB2 = fabsf(ryB1 * rx0) + 1e-9f;
    const float aB3 = fabsf(ryB1 * rx1) + 1e-9f;
    const float invB = 1.f / (aB0 + aB1 + aB2 + aB3);
    float W00B = aB3, W01B = 0.f, W10B = 0.f, W11B = 0.f;
    if (xs) W01B += aB2; else W00B += aB2;
    if (ysB) W10B += aB1; else W00B += aB1;
    if (ysB && xs) W11B += aB0;
    else if (ysB)  W10B += aB0;
    else if (xs)   W01B += aB0;
    else           W00B += aB0;
    W00B *= invB; W01B *= invB; W10B *= invB; W11B *= invB;

#define DUP2(x) (f16x2){(_Float16)(x), (_Float16)(x)}
    const f16x2 ryAh = DUP2(ryA), ryB1h = DUP2(ryB1);
    const f16x2 rx0h = DUP2(rx0), rx1h = DUP2(rx1);
    const f16x2 thirdh = DUP2(1.f / 3.f);
    const f16x2 W00Ah = DUP2(W00A), W01Ah = DUP2(W01A);
    const f16x2 W00Bh = DUP2(W00B), W01Bh = DUP2(W01B);
    const f16x2 W10h = DUP2(W10B), W11h = DUP2(W11B);
    const f16x2 zeroh = DUP2(0.f);

    const int lo16 = lhi << 4;
    const int rA = cia - r0;
    const int cm = cj - c0, cp = cm + (xs ? 1 : 0);
    const char* cell00 = smem + ((rA * ncc + cm) << 9) + lo16;
    const char* cell01 = smem + ((rA * ncc + cp) << 9) + lo16;
    const char* cell10 = cell00 + (ncc << 9);
    const char* cell11 = cell01 + (ncc << 9);
    const char* uvp = smem + UVB + lo16;
    const f16x8* w2l = (const f16x8*)W2F + l;      // GLOBAL, L1-hot

    f32x4 acc[2][4];
#pragma unroll
    for (int s = 0; s < 2; ++s)
#pragma unroll
        for (int ng = 0; ng < 4; ++ng) acc[s][ng] = (f32x4){0.f, 0.f, 0.f, 0.f};

#pragma unroll
    for (int ks = 0; ks < 8; ++ks) {
        const int ko = ks * 64;
        f16x8 bfr[4];
#pragma unroll
        for (int ng = 0; ng < 4; ++ng) bfr[ng] = w2l[(ks * 4 + ng) * 64];
        f16x8 uraw = *(const f16x8*)(uvp + ko);
        f16x8 vraw = *(const f16x8*)(uvp + 512 + ko);
        const f16x2* uu = (const f16x2*)&uraw;
        const f16x2* vv = (const f16x2*)&vraw;
        f16x8 gv00 = *(const f16x8*)(cell00 + ko);
        f16x8 gv01 = *(const f16x8*)(cell01 + ko);
        const f16x2* g00 = (const f16x2*)&gv00;
        const f16x2* g01 = (const f16x2*)&gv01;
        union { f16x2 h2[4]; f16x8 v8; } HA, HB;
#pragma unroll
        for (int e = 0; e < 4; ++e) {
            f16x2 t00 = g00[e] + ryAh * uu[e] + rx0h * vv[e];
            f16x2 t01 = g01[e] + ryAh * uu[e] + rx1h * vv[e];
            f16x2 t00B = t00 + thirdh * uu[e];
            f16x2 t01B = t01 + thirdh * uu[e];
            t00 = __builtin_elementwise_max(t00, zeroh);
            t01 = __builtin_elementwise_max(t01, zeroh);
            t00B = __builtin_elementwise_max(t00B, zeroh);
            t01B = __builtin_elementwise_max(t01B, zeroh);
            HA.h2[e] = W00Ah * t00 + W01Ah * t01;
            HB.h2[e] = W00Bh * t00B + W01Bh * t01B;
        }
        if (ysB) {                                   // wave-uniform
            f16x8 gv10 = *(const f16x8*)(cell10 + ko);
            f16x8 gv11 = *(const f16x8*)(cell11 + ko);
            const f16x2* g10 = (const f16x2*)&gv10;
            const f16x2* g11 = (const f16x2*)&gv11;
#pragma unroll
            for (int e = 0; e < 4; ++e) {
                f16x2 t10 = g10[e] + ryB1h * uu[e] + rx0h * vv[e];
                f16x2 t11 = g11[e] + ryB1h * uu[e] + rx1h * vv[e];
                HB.h2[e] += W10h * __builtin_elementwise_max(t10, zeroh);
                HB.h2[e] += W11h * __builtin_elementwise_max(t11, zeroh);
            }
        }
#pragma unroll
        for (int ng = 0; ng < 4; ++ng)
            acc[0][ng] = __builtin_amdgcn_mfma_f32_16x16x32_f16(HA.v8, bfr[ng], acc[0][ng], 0, 0, 0);
#pragma unroll
        for (int ng = 0; ng < 4; ++ng)
            acc[1][ng] = __builtin_amdgcn_mfma_f32_16x16x32_f16(HB.v8, bfr[ng], acc[1][ng], 0, 0, 0);
    }

    // ---- epilogue: explicit f32x4 stores (8 dwordx4 per thread)
#pragma unroll
    for (int s = 0; s < 2; ++s) {
        const int irow = ia + s;
#pragma unroll
        for (int ng = 0; ng < 4; ++ng) {
            const int o = (ng << 4) + dj;
            f32x4 ov;
#pragma unroll
            for (int r = 0; r < 4; ++r) ov[r] = acc[s][ng][r] + bbv[ng];
            *(f32x4*)(out + (((size_t)b * NOUT + o) * HOUT + irow) * HOUT + j0 + (lhi << 2)) = ov;
        }
    }
}

extern "C" void kernel_launch(void* const* d_in, const int* in_sizes, int n_in,
                              void* d_out, int out_size, void* d_ws, size_t ws_size,
                              hipStream_t stream) {
    const float* res = (const float*)d_in[0];
    const float* w1  = (const float*)d_in[1];
    const float* b1  = (const float*)d_in[2];
    const float* w2  = (const float*)d_in[3];
    const float* b2  = (const float*)d_in[4];
    float* out = (float*)d_out;

    char* ws = (char*)d_ws;
    _Float16* G   = (_Float16*)ws;                              // 4 MB
    _Float16* W2F = (_Float16*)(ws + (size_t)(8u << 20));       // 32 KB
    _Float16* W1F = (_Float16*)(ws + (size_t)(8u << 20) + 65536);
    _Float16* UVH = (_Float16*)(ws + (size_t)(8u << 20) + 131072);

    k_prep<<<130, 256, 0, stream>>>(w1, w2, W2F, W1F, UVH);
    k_gfeat<<<256, 256, 0, stream>>>(res, W1F, b1, G);
    k_main<<<dim3(24, 24, 2), 512, 0, stream>>>(G, W2F, UVH, b2, out);
}

// Round 17
// 38.930 us; speedup vs baseline: 2.2883x; 1.0480x over previous
//
#include <hip/hip_runtime.h>
#include <hip/hip_bf16.h>

typedef float f32x4 __attribute__((ext_vector_type(4)));
typedef _Float16 f16x2 __attribute__((ext_vector_type(2)));
typedef _Float16 f16x8 __attribute__((ext_vector_type(8)));

#define CC   64
#define HID  256
#define NOUT 64
#define HOUT 384
#define MAXCELL 16                 // 16x16 tile: <=4 cell-rows x 4 cell-cols
// LDS map: G_local[16][512B] @0 (8192) | lds_a[16][160B] @8192 (2560) | uv @10752 (1024)
#define ALDS 8192
#define UVB2 10752
#define SMEMB 11776                // -> 4 blocks/CU (thread-limited), 32 waves/CU

// ---- k_prep: w2 -> W2F frags, w1[0:64] -> W1F frags, w1[64:66] -> UVH f16
__global__ __launch_bounds__(256) void k_prep(const float* __restrict__ w1,
                                              const float* __restrict__ w2,
                                              _Float16* __restrict__ W2F,
                                              _Float16* __restrict__ W1F,
                                              _Float16* __restrict__ UVH) {
    int idx = blockIdx.x * 256 + threadIdx.x;
    if (idx < 16384) {
        int f = idx, e = f & 7, l = (f >> 3) & 63, grp = f >> 9;
        int ks = grp >> 2, ng = grp & 3;
        int k = ks * 32 + ((l >> 4) << 3) + e;
        int n = (ng << 4) + (l & 15);
        W2F[f] = (_Float16)w2[k * NOUT + n];
    } else if (idx < 32768) {
        int f = idx - 16384, e = f & 7, l = (f >> 3) & 63, grp = f >> 9;
        int ks = grp >> 4, ng = grp & 15;
        int k = ks * 32 + ((l >> 4) << 3) + e;
        int n = (ng << 4) + (l & 15);
        W1F[f] = (_Float16)w1[k * HID + n];
    } else if (idx < 32768 + 512) {
        int f = idx - 32768;
        UVH[f] = (_Float16)w1[(CC + (f >> 8)) * HID + (f & 255)];
    }
}

// ---- main (fused): block = 8 waves (512 thr), tile = 16x16 px.
// Prologue computes G_local[cell][256] = b1 + res_f16 @ w1_f16 via MFMA
// (A staged in lds_a, B = W1F from global, L2-hot). Pixel loop identical to R15.
__global__ __launch_bounds__(512, 2) void k_main(const float* __restrict__ res,
                                                 const _Float16* __restrict__ W1F,
                                                 const float* __restrict__ b1,
                                                 const _Float16* __restrict__ W2F,
                                                 const _Float16* __restrict__ UVH,
                                                 const float* __restrict__ b2,
                                                 float* __restrict__ out) {
    const int jt = blockIdx.x;        // 0..23
    const int it = blockIdx.y;        // 0..23
    const int b  = blockIdx.z;        // 0..1
    const int tid = threadIdx.x;
    const int wv = tid >> 6, l = tid & 63;
    const int lhi = l >> 4, dj = l & 15;
    const int i0 = it * 16, j0 = jt * 16;

    __shared__ char smem[SMEMB];

    // ---- integer staged-cell bounds
    const int r0 = i0 / 6;
    const int i15 = i0 + 15, ci15 = i15 / 6;
    const int r1 = min(ci15 + ((i15 - 6 * ci15) == 5 ? 1 : 0), 63);
    const int c0 = j0 / 6;
    const int j15 = j0 + 15, cj15 = j15 / 6;
    const int c1 = min(cj15 + ((j15 - 6 * cj15) == 5 ? 1 : 0), 63);
    const int ncc = c1 - c0 + 1;              // 3 or 4
    const int ncell = (r1 - r0 + 1) * ncc;    // 9..16

    // ---- prologue A: stage res slice -> lds_a[cell][c] (f32->f16 transpose)
#pragma unroll
    for (int t = 0; t < 2; ++t) {
        int idx = t * 512 + tid;              // 0..1023
        int c = idx >> 4, cl = idx & 15;
        if (cl < ncell) {
            int cr = (ncc == 4) ? (cl >> 2) : ((cl * 11) >> 5);
            int cc = cl - cr * ncc;
            float v = res[((b * CC + c) << 12) + ((r0 + cr) << 6) + (c0 + cc)];
            *(_Float16*)(smem + ALDS + cl * 160 + c * 2) = (_Float16)v;
        }
    }
    if (tid < 64)
        *(f32x4*)(smem + UVB2 + (tid << 4)) = *(const f32x4*)(UVH + (tid << 3));
    float bbv[4];
#pragma unroll
    for (int ng = 0; ng < 4; ++ng) bbv[ng] = b2[(ng << 4) + dj];
    __syncthreads();

    // ---- prologue B: G_local[cell][n] via MFMA; wave handles n-groups q0,q0+1
    {
        const int q0 = wv << 1;
        f32x4 accg[2];
#pragma unroll
        for (int q = 0; q < 2; ++q) {
            float bb = b1[(q0 + q) * 16 + dj];
            accg[q] = (f32x4){bb, bb, bb, bb};
        }
#pragma unroll
        for (int ks2 = 0; ks2 < 2; ++ks2) {
            f16x8 afr = *(const f16x8*)(smem + ALDS + dj * 160 + ks2 * 64 + lhi * 16);
#pragma unroll
            for (int q = 0; q < 2; ++q) {
                f16x8 bfr = *(const f16x8*)(W1F + (((ks2 * 16 + q0 + q) * 64 + l) << 3));
                accg[q] = __builtin_amdgcn_mfma_f32_16x16x32_f16(afr, bfr, accg[q], 0, 0, 0);
            }
        }
#pragma unroll
        for (int q = 0; q < 2; ++q) {
            const int n = (q0 + q) * 16 + dj;
#pragma unroll
            for (int r = 0; r < 4; ++r) {
                const int cell = (lhi << 2) + r;      // D row = lhi*4 + r
                *(_Float16*)(smem + (cell << 9) + n * 2) = (_Float16)accg[q][r];
            }
        }
    }
    __syncthreads();

    // ---- x setup (per lane)
    const int j = j0 + dj;
    const int cj = j / 6, pj = j - 6 * cj;
    const bool xs = (pj == 5) && (cj < 63);
    const float rx0 = (float)(2 * pj - 5) * (1.f / 6.f);
    const float rx1 = xs ? rx0 - 2.f : rx0;

    // ---- y setup: strip A = row ia (even => pia in {0,2,4}), strip B = ia+1
    const int ia = i0 + (wv << 1);
    const int cia = ia / 6, pia = ia - 6 * cia;
    const float ryA = (float)(2 * pia - 5) * (1.f / 6.f);
    const float ryB = ryA + (1.f / 3.f);
    const bool ysB = (pia == 4) && (cia < 63);
    const float ryB1 = ysB ? ryB - 2.f : ryB;

    const float aA0 = fabsf(ryA * rx0) + 1e-9f;
    const float aA1 = fabsf(ryA * rx1) + 1e-9f;
    const float invA = 1.f / (aA0 + aA1);
    const float W00A = xs ? aA1 * invA : 1.f;
    const float W01A = xs ? aA0 * invA : 0.f;
    const float aB0 = fabsf(ryB * rx0) + 1e-9f;
    const float aB1 = fabsf(ryB * rx1) + 1e-9f;
    const float aB2 = fabsf(ryB1 * rx0) + 1e-9f;
    const float aB3 = fabsf(ryB1 * rx1) + 1e-9f;
    const float invB = 1.f / (aB0 + aB1 + aB2 + aB3);
    float W00B = aB3, W01B = 0.f, W10B = 0.f, W11B = 0.f;
    if (xs) W01B += aB2; else W00B += aB2;
    if (ysB) W10B += aB1; else W00B += aB1;
    if (ysB && xs) W11B += aB0;
    else if (ysB)  W10B += aB0;
    else if (xs)   W01B += aB0;
    else           W00B += aB0;
    W00B *= invB; W01B *= invB; W10B *= invB; W11B *= invB;

#define DUP2(x) (f16x2){(_Float16)(x), (_Float16)(x)}
    const f16x2 ryAh = DUP2(ryA), ryB1h = DUP2(ryB1);
    const f16x2 rx0h = DUP2(rx0), rx1h = DUP2(rx1);
    const f16x2 thirdh = DUP2(1.f / 3.f);
    const f16x2 W00Ah = DUP2(W00A), W01Ah = DUP2(W01A);
    const f16x2 W00Bh = DUP2(W00B), W01Bh = DUP2(W01B);
    const f16x2 W10h = DUP2(W10B), W11h = DUP2(W11B);
    const f16x2 zeroh = DUP2(0.f);

    const int lo16 = lhi << 4;
    const int rA = cia - r0;
    const int cm = cj - c0, cp = cm + (xs ? 1 : 0);
    const char* cell00 = smem + ((rA * ncc + cm) << 9) + lo16;
    const char* cell01 = smem + ((rA * ncc + cp) << 9) + lo16;
    const char* cell10 = cell00 + (ncc << 9);
    const char* cell11 = cell01 + (ncc << 9);
    const char* uvp = smem + UVB2 + lo16;
    const f16x8* w2l = (const f16x8*)W2F + l;      // GLOBAL, L1/L2-hot

    f32x4 acc[2][4];
#pragma unroll
    for (int s = 0; s < 2; ++s)
#pragma unroll
        for (int ng = 0; ng < 4; ++ng) acc[s][ng] = (f32x4){0.f, 0.f, 0.f, 0.f};

#pragma unroll
    for (int ks = 0; ks < 8; ++ks) {
        const int ko = ks * 64;
        f16x8 bfr[4];
#pragma unroll
        for (int ng = 0; ng < 4; ++ng) bfr[ng] = w2l[(ks * 4 + ng) * 64];
        f16x8 uraw = *(const f16x8*)(uvp + ko);
        f16x8 vraw = *(const f16x8*)(uvp + 512 + ko);
        const f16x2* uu = (const f16x2*)&uraw;
        const f16x2* vv = (const f16x2*)&vraw;
        f16x8 gv00 = *(const f16x8*)(cell00 + ko);
        f16x8 gv01 = *(const f16x8*)(cell01 + ko);
        const f16x2* g00 = (const f16x2*)&gv00;
        const f16x2* g01 = (const f16x2*)&gv01;
        union { f16x2 h2[4]; f16x8 v8; } HA, HB;
#pragma unroll
        for (int e = 0; e < 4; ++e) {
            f16x2 t00 = g00[e] + ryAh * uu[e] + rx0h * vv[e];
            f16x2 t01 = g01[e] + ryAh * uu[e] + rx1h * vv[e];
            f16x2 t00B = t00 + thirdh * uu[e];
            f16x2 t01B = t01 + thirdh * uu[e];
            t00 = __builtin_elementwise_max(t00, zeroh);
            t01 = __builtin_elementwise_max(t01, zeroh);
            t00B = __builtin_elementwise_max(t00B, zeroh);
            t01B = __builtin_elementwise_max(t01B, zeroh);
            HA.h2[e] = W00Ah * t00 + W01Ah * t01;
            HB.h2[e] = W00Bh * t00B + W01Bh * t01B;
        }
        if (ysB) {                                   // wave-uniform
            f16x8 gv10 = *(const f16x8*)(cell10 + ko);
            f16x8 gv11 = *(const f16x8*)(cell11 + ko);
            const f16x2* g10 = (const f16x2*)&gv10;
            const f16x2* g11 = (const f16x2*)&gv11;
#pragma unroll
            for (int e = 0; e < 4; ++e) {
                f16x2 t10 = g10[e] + ryB1h * uu[e] + rx0h * vv[e];
                f16x2 t11 = g11[e] + ryB1h * uu[e] + rx1h * vv[e];
                HB.h2[e] += W10h * __builtin_elementwise_max(t10, zeroh);
                HB.h2[e] += W11h * __builtin_elementwise_max(t11, zeroh);
            }
        }
#pragma unroll
        for (int ng = 0; ng < 4; ++ng)
            acc[0][ng] = __builtin_amdgcn_mfma_f32_16x16x32_f16(HA.v8, bfr[ng], acc[0][ng], 0, 0, 0);
#pragma unroll
        for (int ng = 0; ng < 4; ++ng)
            acc[1][ng] = __builtin_amdgcn_mfma_f32_16x16x32_f16(HB.v8, bfr[ng], acc[1][ng], 0, 0, 0);
    }

    // ---- epilogue: explicit f32x4 stores (8 dwordx4 per thread)
#pragma unroll
    for (int s = 0; s < 2; ++s) {
        const int irow = ia + s;
#pragma unroll
        for (int ng = 0; ng < 4; ++ng) {
            const int o = (ng << 4) + dj;
            f32x4 ov;
#pragma unroll
            for (int r = 0; r < 4; ++r) ov[r] = acc[s][ng][r] + bbv[ng];
            *(f32x4*)(out + (((size_t)b * NOUT + o) * HOUT + irow) * HOUT + j0 + (lhi << 2)) = ov;
        }
    }
}

extern "C" void kernel_launch(void* const* d_in, const int* in_sizes, int n_in,
                              void* d_out, int out_size, void* d_ws, size_t ws_size,
                              hipStream_t stream) {
    const float* res = (const float*)d_in[0];
    const float* w1  = (const float*)d_in[1];
    const float* b1  = (const float*)d_in[2];
    const float* w2  = (const float*)d_in[3];
    const float* b2  = (const float*)d_in[4];
    float* out = (float*)d_out;

    char* ws = (char*)d_ws;
    _Float16* W2F = (_Float16*)(ws + (size_t)(8u << 20));       // 32 KB
    _Float16* W1F = (_Float16*)(ws + (size_t)(8u << 20) + 65536);
    _Float16* UVH = (_Float16*)(ws + (size_t)(8u << 20) + 131072);

    k_prep<<<130, 256, 0, stream>>>(w1, w2, W2F, W1F, UVH);
    k_main<<<dim3(24, 24, 2), 512, 0, stream>>>(res, W1F, b1, W2F, UVH, b2, out);
}